// Round 5
// baseline (1950.137 us; speedup 1.0000x reference)
//
#include <hip/hip_runtime.h>
#include <hip/hip_bf16.h>
#include <hip/hip_cooperative_groups.h>

// ChildSumTreeLSTM, fp32 in/out, depth=17, N=2^18-1, D_IN=H=128.
// R5: ONE cooperative kernel for the entire tree. grid.sync() between levels.
//  - x@W fused into each level tile (no X intermediate at all).
//  - Leaves done in a streaming phase (3-gate GEMM, in-lane epilogue).
//  - All global reads/writes vectorized (16B); h/c written via LDS transpose.
//  - Shifted indexing: buffer row = node_id + 1 -> every level 32-aligned.
//  - Weights: W plain bf16 (x-path error per-node random), U split-2 hi/lo.
//  - h stored bf16, c stored fp32.

namespace cg = cooperative_groups;

typedef __bf16 bf16_t;
typedef __bf16 bf16x8 __attribute__((ext_vector_type(8)));
typedef float  f32x4  __attribute__((ext_vector_type(4)));

#define MFMA16(a, b, c) __builtin_amdgcn_mfma_f32_16x16x32_bf16((a), (b), (c), 0, 0, 0)

__device__ __forceinline__ float sigm(float x) { return 1.0f / (1.0f + __expf(-x)); }
__device__ __forceinline__ float tanh_(float x) {
    float a = fabsf(x);
    float e = __expf(2.0f * a);
    float t = 1.0f - 2.0f / (e + 1.0f);
    return copysignf(t, x);
}

__device__ __forceinline__ void cvt16(const float* __restrict__ src, bf16_t* __restrict__ dst)
{
    float tmp[16];
    *(float4*)&tmp[0]  = ((const float4*)src)[0];
    *(float4*)&tmp[4]  = ((const float4*)src)[1];
    *(float4*)&tmp[8]  = ((const float4*)src)[2];
    *(float4*)&tmp[12] = ((const float4*)src)[3];
    bf16_t b[16];
#pragma unroll
    for (int j = 0; j < 16; j++) b[j] = (bf16_t)tmp[j];
    *(bf16x8*)&dst[0] = *(bf16x8*)&b[0];
    *(bf16x8*)&dst[8] = *(bf16x8*)&b[8];
}

__device__ __forceinline__ void zero16(bf16_t* __restrict__ dst)
{
    bf16x8 z = (bf16x8)(bf16_t)0.f;
    *(bf16x8*)&dst[0] = z;
    *(bf16x8*)&dst[8] = z;
}

// SW element layout (bf16 elems):
//   W slot g (0=Wi 1=Wf 2=Wo 3=Wu): base g*16384, plain bf16.
//   U slot u (0=Ui 1=Uf 2=Uo 3=Uu): base 65536 + u*32768 (hi), +16384 (lo).
//   idx = ((nt*4+kb)*64 + lane)*8 + j ; elem = M[kb*32+(lane>>4)*8+j][nt*16+(lane&15)]

__global__ __launch_bounds__(256, 3)
void k_tree(const float* __restrict__ x,
            const float* __restrict__ Wi, const float* __restrict__ bi,
            const float* __restrict__ Ui,
            const float* __restrict__ Wf, const float* __restrict__ bf_,
            const float* __restrict__ Uf,
            const float* __restrict__ Wo, const float* __restrict__ bo,
            const float* __restrict__ Uo,
            const float* __restrict__ Wu, const float* __restrict__ bu,
            const float* __restrict__ Uu,
            bf16_t* __restrict__ SW, bf16_t* __restrict__ H,
            float* __restrict__ C, float* __restrict__ out, int depth)
{
    __shared__ __align__(16) char smem[42496];
    bf16_t (*XA)[136]  = (bf16_t(*)[136])(smem);            // 0 .. 8704   staging (parents' x)
    bf16_t (*HC)[136]  = (bf16_t(*)[136])(smem + 8704);     // .. 26112    staging (children h)
    bf16_t (*HT)[136]  = (bf16_t(*)[136])(smem + 26112);    // .. 34816    child-sum
    float  (*SXf)[132] = (float(*)[132])(smem);             // 0 .. 16896  alias (post K-loop)
    float  (*Sex)[132] = (float(*)[132])(smem + 16896);     // .. 33792    f*c exchange
    bf16_t (*Hd)[136]  = (bf16_t(*)[136])(smem + 33792);    // .. 42496    h transpose tile
    float  (*Cd)[132]  = (float(*)[132])(smem);             // 0 .. 16896  alias (post f-path)

    const int tid  = threadIdx.x;
    const int wave = tid >> 6, lane = tid & 63;
    const int quad = lane >> 4, lc = lane & 15;
    const int NL = 1 << depth, Ntot = 2 * NL - 1;

    cg::grid_group grid = cg::this_grid();

    // ================= phase P: weight swizzle (8 blocks) =================
    if (blockIdx.x < 8) {
        int b = blockIdx.x;
        const float* src;
        switch (b) {
            case 0: src = Wi; break; case 1: src = Wf; break;
            case 2: src = Wo; break; case 3: src = Wu; break;
            case 4: src = Ui; break; case 5: src = Uf; break;
            case 6: src = Uo; break; default: src = Uu; break;
        }
        if (b < 4) {
            bf16_t* hi = SW + (size_t)b * 16384;
            for (int idx = tid; idx < 16384; idx += 256) {
                int j = idx & 7, ln = (idx >> 3) & 63, kb = (idx >> 9) & 3, nt = idx >> 11;
                int k = kb * 32 + (ln >> 4) * 8 + j;
                int n = nt * 16 + (ln & 15);
                hi[idx] = (bf16_t)src[k * 128 + n];
            }
        } else {
            bf16_t* hi = SW + 65536 + (size_t)(b - 4) * 32768;
            bf16_t* lo = hi + 16384;
            for (int idx = tid; idx < 16384; idx += 256) {
                int j = idx & 7, ln = (idx >> 3) & 63, kb = (idx >> 9) & 3, nt = idx >> 11;
                int k = kb * 32 + (ln >> 4) * 8 + j;
                int n = nt * 16 + (ln & 15);
                float w = src[k * 128 + n];
                bf16_t hh = (bf16_t)w;
                hi[idx] = hh;
                lo[idx] = (bf16_t)(w - (float)hh);
            }
        }
    }
    grid.sync();

    // ================= phase L: leaves =================
    // leaf shifted rows: [NL, 2NL), 32-row tiles, exact.
    for (int t = blockIdx.x; t < (NL >> 5); t += gridDim.x) {
        const int s0 = NL + 32 * t;
        {   // stage x rows: node v = s0 + r - 1
            int r = tid >> 3, cb = (tid & 7) * 16;
            cvt16(x + (size_t)(s0 + r - 1) * 128 + cb, &XA[r][cb]);
        }
        __syncthreads();

        f32x4 aI[2][2], aO[2][2], aU[2][2];
#pragma unroll
        for (int nt = 0; nt < 2; nt++)
#pragma unroll
            for (int mt = 0; mt < 2; mt++) {
                aI[nt][mt] = (f32x4){0.f, 0.f, 0.f, 0.f};
                aO[nt][mt] = (f32x4){0.f, 0.f, 0.f, 0.f};
                aU[nt][mt] = (f32x4){0.f, 0.f, 0.f, 0.f};
            }
        for (int kb = 0; kb < 4; kb++) {
            const int k0 = kb * 32 + quad * 8;
            bf16x8 a0 = *(const bf16x8*)&XA[lc][k0];
            bf16x8 a1 = *(const bf16x8*)&XA[16 + lc][k0];
#pragma unroll
            for (int nt = 0; nt < 2; nt++) {
                const size_t boff = ((size_t)((2 * wave + nt) * 4 + kb) * 64 + lane) * 8;
                bf16x8 bWi = *(const bf16x8*)(SW + boff);
                bf16x8 bWo = *(const bf16x8*)(SW + 32768 + boff);
                bf16x8 bWu = *(const bf16x8*)(SW + 49152 + boff);
                aI[nt][0] = MFMA16(a0, bWi, aI[nt][0]);
                aI[nt][1] = MFMA16(a1, bWi, aI[nt][1]);
                aO[nt][0] = MFMA16(a0, bWo, aO[nt][0]);
                aO[nt][1] = MFMA16(a1, bWo, aO[nt][1]);
                aU[nt][0] = MFMA16(a0, bWu, aU[nt][0]);
                aU[nt][1] = MFMA16(a1, bWu, aU[nt][1]);
            }
        }
        // in-lane epilogue: h -> Hd, c kept in regs
        float cvr[2][2][4];
#pragma unroll
        for (int nt = 0; nt < 2; nt++) {
            const int col = (2 * wave + nt) * 16 + lc;
            float bii = bi[col], boi = bo[col], bui = bu[col];
#pragma unroll
            for (int mt = 0; mt < 2; mt++)
#pragma unroll
                for (int r = 0; r < 4; r++) {
                    float iv = sigm(aI[nt][mt][r] + bii);
                    float ov = sigm(aO[nt][mt][r] + boi);
                    float uv = tanh_(aU[nt][mt][r] + bui);
                    float cv = iv * uv;
                    Hd[mt * 16 + quad * 4 + r][col] = (bf16_t)(ov * tanh_(cv));
                    cvr[nt][mt][r] = cv;
                }
        }
        __syncthreads();
        {   // h out (vector) + Cd dump
            int r = tid >> 3, cb = (tid & 7) * 16;
            uint4* dst = (uint4*)(H + (size_t)(s0 + r) * 128 + cb);
            dst[0] = *(uint4*)&Hd[r][cb];
            dst[1] = *(uint4*)&Hd[r][cb + 8];
        }
#pragma unroll
        for (int nt = 0; nt < 2; nt++)
#pragma unroll
            for (int mt = 0; mt < 2; mt++)
#pragma unroll
                for (int r = 0; r < 4; r++)
                    Cd[mt * 16 + quad * 4 + r][(2 * wave + nt) * 16 + lc] = cvr[nt][mt][r];
        __syncthreads();
        {   // c out (vector)
            int r = tid >> 3, cb = (tid & 7) * 16;
            float4* dst = (float4*)(C + (size_t)(s0 + r) * 128 + cb);
            dst[0] = *(float4*)&Cd[r][cb];
            dst[1] = *(float4*)&Cd[r][cb + 4];
            dst[2] = *(float4*)&Cd[r][cb + 8];
            dst[3] = *(float4*)&Cd[r][cb + 12];
        }
        __syncthreads();   // protect Cd/Hd before next tile's staging
    }
    grid.sync();

    // ================= levels bottom-up =================
    for (int l = depth - 1; l >= 0; --l) {
        const int P  = 1 << l;                 // parents this level; base shifted row = P
        const int T  = (P + 31) >> 5;
        const int Pt = (P < 32) ? P : 32;
        for (int t = blockIdx.x; t < T; t += gridDim.x) {
            const int s0 = P + 32 * t;
            {   // stage parents' x
                int r = tid >> 3, cb = (tid & 7) * 16;
                if (r < Pt) cvt16(x + (size_t)(s0 + r - 1) * 128 + cb, &XA[r][cb]);
                else        zero16(&XA[r][cb]);
            }
            {   // stage children h (shifted rows 2*s0 + r)
                int r = tid >> 2, cb = (tid & 3) * 32;
                if (r < 2 * Pt) {
                    const uint4* src = (const uint4*)(H + (size_t)(2 * s0 + r) * 128 + cb);
                    *(uint4*)&HC[r][cb]      = src[0];
                    *(uint4*)&HC[r][cb + 8]  = src[1];
                    *(uint4*)&HC[r][cb + 16] = src[2];
                    *(uint4*)&HC[r][cb + 24] = src[3];
                } else {
                    uint4 z = {0u, 0u, 0u, 0u};
                    *(uint4*)&HC[r][cb]      = z;
                    *(uint4*)&HC[r][cb + 8]  = z;
                    *(uint4*)&HC[r][cb + 16] = z;
                    *(uint4*)&HC[r][cb + 24] = z;
                }
            }
            __syncthreads();
            for (int ci = tid; ci < 512; ci += 256) {   // child-sum
                int m = ci >> 4, j0 = (ci & 15) * 8;
                bf16x8 h0 = *(const bf16x8*)&HC[2 * m][j0];
                bf16x8 h1 = *(const bf16x8*)&HC[2 * m + 1][j0];
                bf16_t s[8];
#pragma unroll
                for (int j = 0; j < 8; j++) s[j] = (bf16_t)((float)h0[j] + (float)h1[j]);
                *(bf16x8*)&HT[m][j0] = *(bf16x8*)&s[0];
            }
            __syncthreads();

            f32x4 aI[2][2], aO[2][2], aU[2][2], aXf[2][2], aF[2][4];
#pragma unroll
            for (int nt = 0; nt < 2; nt++) {
#pragma unroll
                for (int mt = 0; mt < 2; mt++) {
                    aI[nt][mt]  = (f32x4){0.f, 0.f, 0.f, 0.f};
                    aO[nt][mt]  = (f32x4){0.f, 0.f, 0.f, 0.f};
                    aU[nt][mt]  = (f32x4){0.f, 0.f, 0.f, 0.f};
                    aXf[nt][mt] = (f32x4){0.f, 0.f, 0.f, 0.f};
                }
#pragma unroll
                for (int mt = 0; mt < 4; mt++) aF[nt][mt] = (f32x4){0.f, 0.f, 0.f, 0.f};
            }

            for (int kb = 0; kb < 4; kb++) {
                const int k0 = kb * 32 + quad * 8;
                bf16x8 ax0 = *(const bf16x8*)&XA[lc][k0];
                bf16x8 ax1 = *(const bf16x8*)&XA[16 + lc][k0];
                bf16x8 at0 = *(const bf16x8*)&HT[lc][k0];
                bf16x8 at1 = *(const bf16x8*)&HT[16 + lc][k0];
                bf16x8 ac0 = *(const bf16x8*)&HC[lc][k0];
                bf16x8 ac1 = *(const bf16x8*)&HC[16 + lc][k0];
                bf16x8 ac2 = *(const bf16x8*)&HC[32 + lc][k0];
                bf16x8 ac3 = *(const bf16x8*)&HC[48 + lc][k0];
#pragma unroll
                for (int nt = 0; nt < 2; nt++) {
                    const size_t boff = ((size_t)((2 * wave + nt) * 4 + kb) * 64 + lane) * 8;
                    // x @ W (plain bf16)
                    bf16x8 bWi = *(const bf16x8*)(SW + boff);
                    bf16x8 bWf = *(const bf16x8*)(SW + 16384 + boff);
                    bf16x8 bWo = *(const bf16x8*)(SW + 32768 + boff);
                    bf16x8 bWu = *(const bf16x8*)(SW + 49152 + boff);
                    aI[nt][0]  = MFMA16(ax0, bWi, aI[nt][0]);
                    aI[nt][1]  = MFMA16(ax1, bWi, aI[nt][1]);
                    aXf[nt][0] = MFMA16(ax0, bWf, aXf[nt][0]);
                    aXf[nt][1] = MFMA16(ax1, bWf, aXf[nt][1]);
                    aO[nt][0]  = MFMA16(ax0, bWo, aO[nt][0]);
                    aO[nt][1]  = MFMA16(ax1, bWo, aO[nt][1]);
                    aU[nt][0]  = MFMA16(ax0, bWu, aU[nt][0]);
                    aU[nt][1]  = MFMA16(ax1, bWu, aU[nt][1]);
                    // ht @ U (split-2)
                    const bf16_t* Ub = SW + 65536;
                    bf16x8 bIh = *(const bf16x8*)(Ub + boff);
                    bf16x8 bIl = *(const bf16x8*)(Ub + 16384 + boff);
                    aI[nt][0] = MFMA16(at0, bIh, aI[nt][0]);
                    aI[nt][0] = MFMA16(at0, bIl, aI[nt][0]);
                    aI[nt][1] = MFMA16(at1, bIh, aI[nt][1]);
                    aI[nt][1] = MFMA16(at1, bIl, aI[nt][1]);
                    bf16x8 bOh = *(const bf16x8*)(Ub + 65536 + boff);
                    bf16x8 bOl = *(const bf16x8*)(Ub + 81920 + boff);
                    aO[nt][0] = MFMA16(at0, bOh, aO[nt][0]);
                    aO[nt][0] = MFMA16(at0, bOl, aO[nt][0]);
                    aO[nt][1] = MFMA16(at1, bOh, aO[nt][1]);
                    aO[nt][1] = MFMA16(at1, bOl, aO[nt][1]);
                    bf16x8 bUh = *(const bf16x8*)(Ub + 98304 + boff);
                    bf16x8 bUl = *(const bf16x8*)(Ub + 114688 + boff);
                    aU[nt][0] = MFMA16(at0, bUh, aU[nt][0]);
                    aU[nt][0] = MFMA16(at0, bUl, aU[nt][0]);
                    aU[nt][1] = MFMA16(at1, bUh, aU[nt][1]);
                    aU[nt][1] = MFMA16(at1, bUl, aU[nt][1]);
                    // hc @ Uf (split-2, 64 child rows)
                    bf16x8 bFh = *(const bf16x8*)(Ub + 32768 + boff);
                    bf16x8 bFl = *(const bf16x8*)(Ub + 49152 + boff);
                    aF[nt][0] = MFMA16(ac0, bFh, aF[nt][0]);
                    aF[nt][0] = MFMA16(ac0, bFl, aF[nt][0]);
                    aF[nt][1] = MFMA16(ac1, bFh, aF[nt][1]);
                    aF[nt][1] = MFMA16(ac1, bFl, aF[nt][1]);
                    aF[nt][2] = MFMA16(ac2, bFh, aF[nt][2]);
                    aF[nt][2] = MFMA16(ac2, bFl, aF[nt][2]);
                    aF[nt][3] = MFMA16(ac3, bFh, aF[nt][3]);
                    aF[nt][3] = MFMA16(ac3, bFl, aF[nt][3]);
                }
            }
            __syncthreads();   // staging reads done; alias regions become writable

            // dump Xf (+bias) for cross-thread f-path
#pragma unroll
            for (int nt = 0; nt < 2; nt++) {
                const int col = (2 * wave + nt) * 16 + lc;
                float bfv = bf_[col];
#pragma unroll
                for (int mt = 0; mt < 2; mt++)
#pragma unroll
                    for (int r = 0; r < 4; r++)
                        SXf[mt * 16 + quad * 4 + r][col] = aXf[nt][mt][r] + bfv;
            }
            __syncthreads();

            // f-path: S[pl][col] = f0*c0 + f1*c1 (children in-lane reg pairs)
#pragma unroll
            for (int nt = 0; nt < 2; nt++) {
                const int col = (2 * wave + nt) * 16 + lc;
#pragma unroll
                for (int mt = 0; mt < 4; mt++)
#pragma unroll
                    for (int pi = 0; pi < 2; pi++) {
                        int pl = mt * 8 + quad * 2 + pi;
                        float xf = SXf[pl][col];
                        float f0 = sigm(xf + aF[nt][mt][2 * pi]);
                        float f1 = sigm(xf + aF[nt][mt][2 * pi + 1]);
                        size_t crow = (size_t)(2 * (s0 + pl)) * 128;
                        float c0 = C[crow + col];
                        float c1 = C[crow + 128 + col];
                        Sex[pl][col] = f0 * c0 + f1 * c1;
                    }
            }
            __syncthreads();

            // i/o/u + cell update; h -> Hd, c in regs
            float cvr[2][2][4];
#pragma unroll
            for (int nt = 0; nt < 2; nt++) {
                const int col = (2 * wave + nt) * 16 + lc;
                float bii = bi[col], boi = bo[col], bui = bu[col];
#pragma unroll
                for (int mt = 0; mt < 2; mt++)
#pragma unroll
                    for (int r = 0; r < 4; r++) {
                        int pl = mt * 16 + quad * 4 + r;
                        float iv = sigm(aI[nt][mt][r] + bii);
                        float ov = sigm(aO[nt][mt][r] + boi);
                        float uv = tanh_(aU[nt][mt][r] + bui);
                        float cv = iv * uv + Sex[pl][col];
                        Hd[pl][col] = (bf16_t)(ov * tanh_(cv));
                        cvr[nt][mt][r] = cv;
                    }
            }
            __syncthreads();

            {   // h out (vector, masked rows) + Cd dump
                int r = tid >> 3, cb = (tid & 7) * 16;
                if (r < Pt) {
                    uint4* dst = (uint4*)(H + (size_t)(s0 + r) * 128 + cb);
                    dst[0] = *(uint4*)&Hd[r][cb];
                    dst[1] = *(uint4*)&Hd[r][cb + 8];
                }
            }
#pragma unroll
            for (int nt = 0; nt < 2; nt++)
#pragma unroll
                for (int mt = 0; mt < 2; mt++)
#pragma unroll
                    for (int r = 0; r < 4; r++)
                        Cd[mt * 16 + quad * 4 + r][(2 * wave + nt) * 16 + lc] = cvr[nt][mt][r];
            __syncthreads();
            {   // c out (vector, masked rows)
                int r = tid >> 3, cb = (tid & 7) * 16;
                if (r < Pt) {
                    float4* dst = (float4*)(C + (size_t)(s0 + r) * 128 + cb);
                    dst[0] = *(float4*)&Cd[r][cb];
                    dst[1] = *(float4*)&Cd[r][cb + 4];
                    dst[2] = *(float4*)&Cd[r][cb + 8];
                    dst[3] = *(float4*)&Cd[r][cb + 12];
                }
            }
            __syncthreads();   // protect aliases before next tile staging
        }
        grid.sync();
    }

    // ================= output: root = shifted row 1 =================
    if (blockIdx.x == 0) {
        if (tid < 128)       out[tid] = (float)H[128 + tid];
        else if (tid < 256)  out[tid] = C[tid];   // C[128 + (tid-128)]
    }
}

// ---------------------------------------------------------------------------
extern "C" void kernel_launch(void* const* d_in, const int* in_sizes, int n_in,
                              void* d_out, int out_size, void* d_ws, size_t ws_size,
                              hipStream_t stream)
{
    const float* x   = (const float*)d_in[0];
    const float* Wi  = (const float*)d_in[1];
    const float* bi  = (const float*)d_in[2];
    const float* Ui  = (const float*)d_in[3];
    const float* Wf  = (const float*)d_in[4];
    const float* bf_ = (const float*)d_in[5];
    const float* Uf  = (const float*)d_in[6];
    const float* Wo  = (const float*)d_in[7];
    const float* bo  = (const float*)d_in[8];
    const float* Uo  = (const float*)d_in[9];
    const float* Wu  = (const float*)d_in[10];
    const float* bu  = (const float*)d_in[11];
    const float* Uu  = (const float*)d_in[12];

    int Ntot  = in_sizes[0] / 128;
    int depth = 31 - __builtin_clz((unsigned)(Ntot + 1)) - 1;
    int NL    = 1 << depth;
    (void)NL;

    // workspace: SW 384KB | H bf16 (Ntot+1)x128 | C fp32 (Ntot+1)x128  (~202 MiB)
    char* w = (char*)d_ws;
    bf16_t* SW = (bf16_t*)w;  w += 393216;
    bf16_t* H  = (bf16_t*)w;  w += (size_t)(Ntot + 1) * 128 * sizeof(bf16_t);
    float*  C  = (float*)w;
    float*  outp = (float*)d_out;

    // size the cooperative grid to guaranteed co-residency
    int maxB = 0;
    hipOccupancyMaxActiveBlocksPerMultiprocessor(&maxB, k_tree, 256, 0);
    if (maxB < 1) maxB = 1;
    int nCU = 0;
    hipDeviceGetAttribute(&nCU, hipDeviceAttributeMultiprocessorCount, 0);
    if (nCU < 1) nCU = 256;
    int nblk = maxB * nCU;
    if (nblk > 1024) nblk = 1024;

    void* args[] = {
        (void*)&x,
        (void*)&Wi, (void*)&bi, (void*)&Ui,
        (void*)&Wf, (void*)&bf_, (void*)&Uf,
        (void*)&Wo, (void*)&bo, (void*)&Uo,
        (void*)&Wu, (void*)&bu, (void*)&Uu,
        (void*)&SW, (void*)&H, (void*)&C, (void*)&outp, (void*)&depth
    };
    hipLaunchCooperativeKernel((const void*)k_tree, dim3(nblk), dim3(256),
                               args, 0, stream);
}

// Round 6
// 722.841 us; speedup vs baseline: 2.6979x; 2.6979x over previous
//
#include <hip/hip_runtime.h>
#include <hip/hip_bf16.h>

// ChildSumTreeLSTM, fp32 in/out, depth=17, N=2^18-1, D_IN=H=128.
// R6: pairwise level fusion. k_pair(A) computes level A+1 (B) entirely in LDS
// (from x + global bottom h/c at level A+2, or pure x@W when B = leaves) and
// then level A, writing only level-A h/c to HBM. Intermediate (odd) levels and
// leaf h/c never touch HBM. 9 k_pair launches for depth 17.
// Weights: W plain bf16, U split-2 hi/lo bf16 (pre-swizzled to B-frag order).
// h global bf16, c global fp32; in-LDS mid h/c bf16. Shifted rows: row = node+1.

typedef __bf16 bf16_t;
typedef __bf16 bf16x8 __attribute__((ext_vector_type(8)));
typedef float  f32x4  __attribute__((ext_vector_type(4)));

#define MFMA16(a, b, c) __builtin_amdgcn_mfma_f32_16x16x32_bf16((a), (b), (c), 0, 0, 0)

__device__ __forceinline__ float sigm(float x) { return 1.0f / (1.0f + __expf(-x)); }
__device__ __forceinline__ float tanh_(float x) {
    float a = fabsf(x);
    float e = __expf(2.0f * a);
    float t = 1.0f - 2.0f / (e + 1.0f);
    return copysignf(t, x);
}

__device__ __forceinline__ void cvt16(const float* __restrict__ src, bf16_t* __restrict__ dst)
{
    float tmp[16];
    *(float4*)&tmp[0]  = ((const float4*)src)[0];
    *(float4*)&tmp[4]  = ((const float4*)src)[1];
    *(float4*)&tmp[8]  = ((const float4*)src)[2];
    *(float4*)&tmp[12] = ((const float4*)src)[3];
    bf16_t b[16];
#pragma unroll
    for (int j = 0; j < 16; j++) b[j] = (bf16_t)tmp[j];
    *(bf16x8*)&dst[0] = *(bf16x8*)&b[0];
    *(bf16x8*)&dst[8] = *(bf16x8*)&b[8];
}

__device__ __forceinline__ void zero16(bf16_t* __restrict__ dst)
{
    bf16x8 z = (bf16x8)(bf16_t)0.f;
    *(bf16x8*)&dst[0] = z;
    *(bf16x8*)&dst[8] = z;
}

// SW layout (bf16 elems): W g (0=Wi 1=Wf 2=Wo 3=Wu) at g*16384, plain.
// U u (0=Ui 1=Uf 2=Uo 3=Uu) at 65536 + u*32768 (hi), +16384 (lo).
// idx = ((nt*4+kb)*64 + lane)*8 + j ; elem = M[kb*32+(lane>>4)*8+j][nt*16+(lane&15)]
__global__ __launch_bounds__(256)
void k_prep(const float* __restrict__ Wi, const float* __restrict__ Wf,
            const float* __restrict__ Wo, const float* __restrict__ Wu,
            const float* __restrict__ Ui, const float* __restrict__ Uf,
            const float* __restrict__ Uo, const float* __restrict__ Uu,
            bf16_t* __restrict__ SW)
{
    int b = blockIdx.x;
    const float* src;
    switch (b) {
        case 0: src = Wi; break; case 1: src = Wf; break;
        case 2: src = Wo; break; case 3: src = Wu; break;
        case 4: src = Ui; break; case 5: src = Uf; break;
        case 6: src = Uo; break; default: src = Uu; break;
    }
    if (b < 4) {
        bf16_t* hi = SW + (size_t)b * 16384;
        for (int idx = threadIdx.x; idx < 16384; idx += 256) {
            int j = idx & 7, ln = (idx >> 3) & 63, kb = (idx >> 9) & 3, nt = idx >> 11;
            int k = kb * 32 + (ln >> 4) * 8 + j;
            int n = nt * 16 + (ln & 15);
            hi[idx] = (bf16_t)src[k * 128 + n];
        }
    } else {
        bf16_t* hi = SW + 65536 + (size_t)(b - 4) * 32768;
        bf16_t* lo = hi + 16384;
        for (int idx = threadIdx.x; idx < 16384; idx += 256) {
            int j = idx & 7, ln = (idx >> 3) & 63, kb = (idx >> 9) & 3, nt = idx >> 11;
            int k = kb * 32 + (ln >> 4) * 8 + j;
            int n = nt * 16 + (ln & 15);
            float w = src[k * 128 + n];
            bf16_t hh = (bf16_t)w;
            hi[idx] = hh;
            lo[idx] = (bf16_t)(w - (float)hh);
        }
    }
}

// ---------------------------------------------------------------------------
// Leaves: 32 rows, 3-gate x@W, in-lane epilogue -> BH/BC (LDS, bf16).
__device__ __forceinline__ void leaf32(
    const float* __restrict__ x, const bf16_t* __restrict__ SW,
    const float* __restrict__ bi, const float* __restrict__ bo,
    const float* __restrict__ bu,
    bf16_t (* __restrict__ XA)[136],
    bf16_t (* __restrict__ BH)[136], bf16_t (* __restrict__ BC)[136],
    int xRowBase, int valid, int outRowOff, int tid)
{
    {
        int r = tid >> 3, cb = (tid & 7) * 16;
        if (r < valid) cvt16(x + (size_t)(xRowBase + r - 1) * 128 + cb, &XA[r][cb]);
        else           zero16(&XA[r][cb]);
    }
    __syncthreads();
    const int wave = tid >> 6, lane = tid & 63;
    const int quad = lane >> 4, lc = lane & 15;

    f32x4 aI[2][2], aO[2][2], aU[2][2];
#pragma unroll
    for (int nt = 0; nt < 2; nt++)
#pragma unroll
        for (int mt = 0; mt < 2; mt++) {
            aI[nt][mt] = (f32x4){0.f, 0.f, 0.f, 0.f};
            aO[nt][mt] = (f32x4){0.f, 0.f, 0.f, 0.f};
            aU[nt][mt] = (f32x4){0.f, 0.f, 0.f, 0.f};
        }
    for (int kb = 0; kb < 4; kb++) {
        const int k0 = kb * 32 + quad * 8;
        bf16x8 a0 = *(const bf16x8*)&XA[lc][k0];
        bf16x8 a1 = *(const bf16x8*)&XA[16 + lc][k0];
#pragma unroll
        for (int nt = 0; nt < 2; nt++) {
            const size_t boff = ((size_t)((2 * wave + nt) * 4 + kb) * 64 + lane) * 8;
            bf16x8 bWi = *(const bf16x8*)(SW + boff);
            bf16x8 bWo = *(const bf16x8*)(SW + 32768 + boff);
            bf16x8 bWu = *(const bf16x8*)(SW + 49152 + boff);
            aI[nt][0] = MFMA16(a0, bWi, aI[nt][0]);
            aI[nt][1] = MFMA16(a1, bWi, aI[nt][1]);
            aO[nt][0] = MFMA16(a0, bWo, aO[nt][0]);
            aO[nt][1] = MFMA16(a1, bWo, aO[nt][1]);
            aU[nt][0] = MFMA16(a0, bWu, aU[nt][0]);
            aU[nt][1] = MFMA16(a1, bWu, aU[nt][1]);
        }
    }
#pragma unroll
    for (int nt = 0; nt < 2; nt++) {
        const int col = (2 * wave + nt) * 16 + lc;
        float bii = bi[col], boi = bo[col], bui = bu[col];
#pragma unroll
        for (int mt = 0; mt < 2; mt++)
#pragma unroll
            for (int r = 0; r < 4; r++) {
                float iv = sigm(aI[nt][mt][r] + bii);
                float ov = sigm(aO[nt][mt][r] + boi);
                float uv = tanh_(aU[nt][mt][r] + bui);
                float cv = iv * uv;
                int pl = mt * 16 + quad * 4 + r;
                BH[outRowOff + pl][col] = (bf16_t)(ov * tanh_(cv));
                BC[outRowOff + pl][col] = (bf16_t)cv;
            }
    }
    __syncthreads();
}

// ---------------------------------------------------------------------------
// 32 internal nodes: x@W (4 gates) + ht@[Ui|Uo|Uu] + hc@Uf (split-2) + update.
// Children h: CH (64 LDS rows). Children c: global (ccBase) or BCc (LDS).
// Output: BH/BC LDS (outLds) or global H (via Hd transpose) + scalar C.
__device__ __forceinline__ void compute32(
    const float* __restrict__ x, const bf16_t* __restrict__ SW,
    const float* __restrict__ bi, const float* __restrict__ bf_,
    const float* __restrict__ bo, const float* __restrict__ bu,
    bf16_t (* __restrict__ XA)[136], float (* __restrict__ SC)[132],
    const bf16_t (* __restrict__ CH)[136],
    const float* __restrict__ Cglob, int ccBase,
    const bf16_t (* __restrict__ BCc)[136], bool ccLds,
    int xRowBase, int valid,
    bf16_t (* __restrict__ BHo)[136], bf16_t (* __restrict__ BCo)[136], int outRowOff,
    bf16_t* __restrict__ Hg, float* __restrict__ Cg, int outBase,
    bf16_t (* __restrict__ Hd)[136], bool outLds, int tid)
{
    {
        int r = tid >> 3, cb = (tid & 7) * 16;
        if (r < valid) cvt16(x + (size_t)(xRowBase + r - 1) * 128 + cb, &XA[r][cb]);
        else           zero16(&XA[r][cb]);
    }
    __syncthreads();

    const int wave = tid >> 6, lane = tid & 63;
    const int quad = lane >> 4, lc = lane & 15;

    f32x4 aI[2][2], aO[2][2], aU[2][2], aXf[2][2], aF[2][4];
#pragma unroll
    for (int nt = 0; nt < 2; nt++) {
#pragma unroll
        for (int mt = 0; mt < 2; mt++) {
            aI[nt][mt]  = (f32x4){0.f, 0.f, 0.f, 0.f};
            aO[nt][mt]  = (f32x4){0.f, 0.f, 0.f, 0.f};
            aU[nt][mt]  = (f32x4){0.f, 0.f, 0.f, 0.f};
            aXf[nt][mt] = (f32x4){0.f, 0.f, 0.f, 0.f};
        }
#pragma unroll
        for (int mt = 0; mt < 4; mt++) aF[nt][mt] = (f32x4){0.f, 0.f, 0.f, 0.f};
    }

    for (int kb = 0; kb < 4; kb++) {
        const int k0 = kb * 32 + quad * 8;
        bf16x8 xa0 = *(const bf16x8*)&XA[lc][k0];
        bf16x8 xa1 = *(const bf16x8*)&XA[16 + lc][k0];
        // on-the-fly child-sum A-fragments
        bf16x8 h00 = *(const bf16x8*)&CH[2 * lc][k0];
        bf16x8 h01 = *(const bf16x8*)&CH[2 * lc + 1][k0];
        bf16x8 h10 = *(const bf16x8*)&CH[2 * lc + 32][k0];
        bf16x8 h11 = *(const bf16x8*)&CH[2 * lc + 33][k0];
        bf16x8 at0, at1;
#pragma unroll
        for (int j = 0; j < 8; j++) {
            at0[j] = (bf16_t)((float)h00[j] + (float)h01[j]);
            at1[j] = (bf16_t)((float)h10[j] + (float)h11[j]);
        }
        bf16x8 ac0 = *(const bf16x8*)&CH[lc][k0];
        bf16x8 ac1 = *(const bf16x8*)&CH[16 + lc][k0];
        bf16x8 ac2 = *(const bf16x8*)&CH[32 + lc][k0];
        bf16x8 ac3 = *(const bf16x8*)&CH[48 + lc][k0];
#pragma unroll
        for (int nt = 0; nt < 2; nt++) {
            const size_t boff = ((size_t)((2 * wave + nt) * 4 + kb) * 64 + lane) * 8;
            bf16x8 bWi = *(const bf16x8*)(SW + boff);
            bf16x8 bWf = *(const bf16x8*)(SW + 16384 + boff);
            bf16x8 bWo = *(const bf16x8*)(SW + 32768 + boff);
            bf16x8 bWu = *(const bf16x8*)(SW + 49152 + boff);
            aI[nt][0]  = MFMA16(xa0, bWi, aI[nt][0]);
            aI[nt][1]  = MFMA16(xa1, bWi, aI[nt][1]);
            aXf[nt][0] = MFMA16(xa0, bWf, aXf[nt][0]);
            aXf[nt][1] = MFMA16(xa1, bWf, aXf[nt][1]);
            aO[nt][0]  = MFMA16(xa0, bWo, aO[nt][0]);
            aO[nt][1]  = MFMA16(xa1, bWo, aO[nt][1]);
            aU[nt][0]  = MFMA16(xa0, bWu, aU[nt][0]);
            aU[nt][1]  = MFMA16(xa1, bWu, aU[nt][1]);
            const bf16_t* Ub = SW + 65536;
            bf16x8 bIh = *(const bf16x8*)(Ub + boff);
            bf16x8 bIl = *(const bf16x8*)(Ub + 16384 + boff);
            aI[nt][0] = MFMA16(at0, bIh, aI[nt][0]);
            aI[nt][0] = MFMA16(at0, bIl, aI[nt][0]);
            aI[nt][1] = MFMA16(at1, bIh, aI[nt][1]);
            aI[nt][1] = MFMA16(at1, bIl, aI[nt][1]);
            bf16x8 bOh = *(const bf16x8*)(Ub + 65536 + boff);
            bf16x8 bOl = *(const bf16x8*)(Ub + 81920 + boff);
            aO[nt][0] = MFMA16(at0, bOh, aO[nt][0]);
            aO[nt][0] = MFMA16(at0, bOl, aO[nt][0]);
            aO[nt][1] = MFMA16(at1, bOh, aO[nt][1]);
            aO[nt][1] = MFMA16(at1, bOl, aO[nt][1]);
            bf16x8 bUh = *(const bf16x8*)(Ub + 98304 + boff);
            bf16x8 bUl = *(const bf16x8*)(Ub + 114688 + boff);
            aU[nt][0] = MFMA16(at0, bUh, aU[nt][0]);
            aU[nt][0] = MFMA16(at0, bUl, aU[nt][0]);
            aU[nt][1] = MFMA16(at1, bUh, aU[nt][1]);
            aU[nt][1] = MFMA16(at1, bUl, aU[nt][1]);
            bf16x8 bFh = *(const bf16x8*)(Ub + 32768 + boff);
            bf16x8 bFl = *(const bf16x8*)(Ub + 49152 + boff);
            aF[nt][0] = MFMA16(ac0, bFh, aF[nt][0]);
            aF[nt][0] = MFMA16(ac0, bFl, aF[nt][0]);
            aF[nt][1] = MFMA16(ac1, bFh, aF[nt][1]);
            aF[nt][1] = MFMA16(ac1, bFl, aF[nt][1]);
            aF[nt][2] = MFMA16(ac2, bFh, aF[nt][2]);
            aF[nt][2] = MFMA16(ac2, bFl, aF[nt][2]);
            aF[nt][3] = MFMA16(ac3, bFh, aF[nt][3]);
            aF[nt][3] = MFMA16(ac3, bFl, aF[nt][3]);
        }
    }
    __syncthreads();   // XA/CH-staging reads done; SC (alias) becomes writable

    // dump xf (+bias) for the f-path row exchange
#pragma unroll
    for (int nt = 0; nt < 2; nt++) {
        const int col = (2 * wave + nt) * 16 + lc;
        float bfv = bf_[col];
#pragma unroll
        for (int mt = 0; mt < 2; mt++)
#pragma unroll
            for (int r = 0; r < 4; r++)
                SC[mt * 16 + quad * 4 + r][col] = aXf[nt][mt][r] + bfv;
    }
    __syncthreads();

    // f-path: S[pl][col] = f0*c0 + f1*c1, children are in-lane reg pairs
    float Sv[2][4][2];
#pragma unroll
    for (int nt = 0; nt < 2; nt++) {
        const int col = (2 * wave + nt) * 16 + lc;
#pragma unroll
        for (int mt = 0; mt < 4; mt++)
#pragma unroll
            for (int pi = 0; pi < 2; pi++) {
                int pl = mt * 8 + quad * 2 + pi;
                float xf = SC[pl][col];
                float f0 = sigm(xf + aF[nt][mt][2 * pi]);
                float f1 = sigm(xf + aF[nt][mt][2 * pi + 1]);
                float c0, c1;
                if (ccLds) {
                    c0 = (float)BCc[2 * pl][col];
                    c1 = (float)BCc[2 * pl + 1][col];
                } else {
                    size_t cr = (size_t)(ccBase + 2 * pl) * 128 + col;
                    c0 = Cglob[cr];
                    c1 = Cglob[cr + 128];
                }
                Sv[nt][mt][pi] = f0 * c0 + f1 * c1;
            }
    }
    __syncthreads();   // all xf reads done -> SC overwritable in place
#pragma unroll
    for (int nt = 0; nt < 2; nt++) {
        const int col = (2 * wave + nt) * 16 + lc;
#pragma unroll
        for (int mt = 0; mt < 4; mt++)
#pragma unroll
            for (int pi = 0; pi < 2; pi++)
                SC[mt * 8 + quad * 2 + pi][col] = Sv[nt][mt][pi];
    }
    __syncthreads();

    // i/o/u + cell update
    float hr[2][2][4];
#pragma unroll
    for (int nt = 0; nt < 2; nt++) {
        const int col = (2 * wave + nt) * 16 + lc;
        float bii = bi[col], boi = bo[col], bui = bu[col];
#pragma unroll
        for (int mt = 0; mt < 2; mt++)
#pragma unroll
            for (int r = 0; r < 4; r++) {
                int pl = mt * 16 + quad * 4 + r;
                float iv = sigm(aI[nt][mt][r] + bii);
                float ov = sigm(aO[nt][mt][r] + boi);
                float uv = tanh_(aU[nt][mt][r] + bui);
                float cv = iv * uv + SC[pl][col];
                float hv = ov * tanh_(cv);
                hr[nt][mt][r] = hv;
                if (outLds) {
                    BHo[outRowOff + pl][col] = (bf16_t)hv;
                    BCo[outRowOff + pl][col] = (bf16_t)cv;
                } else if (pl < valid) {
                    Cg[(size_t)(outBase + pl) * 128 + col] = cv;
                }
            }
    }
    if (outLds) {
        __syncthreads();   // BH/BC visible; scratch reusable by caller
    } else {
        __syncthreads();   // SC reads done -> Hd (overlapping region) writable
#pragma unroll
        for (int nt = 0; nt < 2; nt++) {
            const int col = (2 * wave + nt) * 16 + lc;
#pragma unroll
            for (int mt = 0; mt < 2; mt++)
#pragma unroll
                for (int r = 0; r < 4; r++)
                    Hd[mt * 16 + quad * 4 + r][col] = (bf16_t)hr[nt][mt][r];
        }
        __syncthreads();
        int r = tid >> 3, cb = (tid & 7) * 16;
        if (r < valid) {
            uint4* dst = (uint4*)(Hg + (size_t)(outBase + r) * 128 + cb);
            dst[0] = *(uint4*)&Hd[r][cb];
            dst[1] = *(uint4*)&Hd[r][cb + 8];
        }
        __syncthreads();
    }
}

// ---------------------------------------------------------------------------
// k_pair: block = 32 level-A parents (shifted base Pa + 32t).
// Phase B: 64 level-(A+1) nodes -> LDS (leaf GEMM or from global bottom h/c).
// Phase A: consume LDS children, write level-A h/c to global.
__global__ __launch_bounds__(256)
void k_pair(const float* __restrict__ x, const bf16_t* __restrict__ SW,
            const float* __restrict__ bi, const float* __restrict__ bf_,
            const float* __restrict__ bo, const float* __restrict__ bu,
            bf16_t* __restrict__ H, float* __restrict__ C,
            int Pa, int leafB)
{
    __shared__ __align__(16) char smem[60928];
    bf16_t (*XA)[136] = (bf16_t(*)[136])(smem);            //  8704 staging
    bf16_t (*HC)[136] = (bf16_t(*)[136])(smem + 8704);     // 17408 bottom-h staging / Hd
    float  (*SC)[132] = (float(*)[132])(smem);             // 16896 scratch (alias, post-K)
    bf16_t (*BH)[136] = (bf16_t(*)[136])(smem + 26112);    // 17408 mid h
    bf16_t (*BC)[136] = (bf16_t(*)[136])(smem + 43520);    // 17408 mid c (bf16)

    const int tid = threadIdx.x;
    const int t   = blockIdx.x;
    const int sA0 = Pa + 32 * t;
    int Pta = Pa - 32 * t; if (Pta > 32) Pta = 32;

    if (Pta < 32) {   // small level: pre-zero mid arrays (invalid rows must be 0)
        bf16x8 z = (bf16x8)(bf16_t)0.f;
        for (int i = tid; i < 64 * 17; i += 256) {   // 64*136/8 = 1088 chunks
            ((bf16x8*)BH)[i] = z;
            ((bf16x8*)BC)[i] = z;
        }
    }

    for (int q = 0; q < 2; q++) {
        int bvalid = 2 * Pa - (64 * t + 32 * q);
        if (bvalid > 32) bvalid = 32;
        if (bvalid <= 0) break;
        if (leafB) {
            leaf32(x, SW, bi, bo, bu, XA, BH, BC,
                   2 * sA0 + 32 * q, bvalid, 32 * q, tid);
        } else {
            {   // stage bottom children h rows: shifted 4*sA0 + 64q + r
                int r = tid >> 2, cb = (tid & 3) * 32;
                if (r < 2 * bvalid) {
                    const uint4* src = (const uint4*)(H + (size_t)(4 * sA0 + 64 * q + r) * 128 + cb);
                    *(uint4*)&HC[r][cb]      = src[0];
                    *(uint4*)&HC[r][cb + 8]  = src[1];
                    *(uint4*)&HC[r][cb + 16] = src[2];
                    *(uint4*)&HC[r][cb + 24] = src[3];
                } else {
                    uint4 z = {0u, 0u, 0u, 0u};
                    *(uint4*)&HC[r][cb]      = z;
                    *(uint4*)&HC[r][cb + 8]  = z;
                    *(uint4*)&HC[r][cb + 16] = z;
                    *(uint4*)&HC[r][cb + 24] = z;
                }
            }
            compute32(x, SW, bi, bf_, bo, bu, XA, SC,
                      (const bf16_t(*)[136])HC,
                      C, 4 * sA0 + 64 * q, nullptr, false,
                      2 * sA0 + 32 * q, bvalid,
                      BH, BC, 32 * q,
                      nullptr, nullptr, 0, nullptr, true, tid);
        }
    }

    // phase A: children = BH/BC (LDS), output global
    compute32(x, SW, bi, bf_, bo, bu, XA, SC,
              (const bf16_t(*)[136])BH,
              nullptr, 0, (const bf16_t(*)[136])BC, true,
              sA0, Pta,
              nullptr, nullptr, 0,
              H, C, sA0, HC, false, tid);
}

__global__ __launch_bounds__(256)
void k_out(const bf16_t* __restrict__ H, const float* __restrict__ C,
           float* __restrict__ out)
{
    int t = threadIdx.x;
    if (t < 128)      out[t] = (float)H[128 + t];   // shifted row 1 = root
    else if (t < 256) out[t] = C[t];                // C[128 + (t-128)]
}

// ---------------------------------------------------------------------------
extern "C" void kernel_launch(void* const* d_in, const int* in_sizes, int n_in,
                              void* d_out, int out_size, void* d_ws, size_t ws_size,
                              hipStream_t stream)
{
    const float* x   = (const float*)d_in[0];
    const float* Wi  = (const float*)d_in[1];
    const float* bi  = (const float*)d_in[2];
    const float* Ui  = (const float*)d_in[3];
    const float* Wf  = (const float*)d_in[4];
    const float* bf_ = (const float*)d_in[5];
    const float* Uf  = (const float*)d_in[6];
    const float* Wo  = (const float*)d_in[7];
    const float* bo  = (const float*)d_in[8];
    const float* Uo  = (const float*)d_in[9];
    const float* Wu  = (const float*)d_in[10];
    const float* bu  = (const float*)d_in[11];
    const float* Uu  = (const float*)d_in[12];

    int Ntot  = in_sizes[0] / 128;
    int depth = 31 - __builtin_clz((unsigned)(Ntot + 1)) - 1;

    // workspace: SW 384 KB | H bf16 (Ntot+1)*128 | C fp32 (Ntot+1)*128  (~193 MiB)
    char* w = (char*)d_ws;
    bf16_t* SW = (bf16_t*)w;  w += 393216;
    bf16_t* H  = (bf16_t*)w;  w += (size_t)(Ntot + 1) * 128 * sizeof(bf16_t);
    float*  C  = (float*)w;

    k_prep<<<8, 256, 0, stream>>>(Wi, Wf, Wo, Wu, Ui, Uf, Uo, Uu, SW);

    {   // A = depth-1, B = leaves
        int Pa = 1 << (depth - 1);
        int blocks = (Pa + 31) / 32;
        k_pair<<<blocks, 256, 0, stream>>>(x, SW, bi, bf_, bo, bu, H, C, Pa, 1);
    }
    for (int A = depth - 3; A >= 0; A -= 2) {
        int Pa = 1 << A;
        int blocks = (Pa + 31) / 32;
        k_pair<<<blocks, 256, 0, stream>>>(x, SW, bi, bf_, bo, bu, H, C, Pa, 0);
    }
    if ((depth & 1) == 0) {   // parity fallback (not hit at depth=17)
        k_pair<<<1, 256, 0, stream>>>(x, SW, bi, bf_, bo, bu, H, C, 1, 0);
    }
    k_out<<<1, 256, 0, stream>>>(H, C, (float*)d_out);
}